// Round 2
// baseline (317.521 us; speedup 1.0000x reference)
//
#include <hip/hip_runtime.h>
#include <hip/hip_bf16.h>
#include <math.h>

#define N_V 100000
#define N_E 600000
#define N_F 200000
// CIN = COUT = 128, H = 32

typedef __attribute__((ext_vector_type(8))) short bf16x8;
typedef __attribute__((ext_vector_type(4))) float f32x4;

#define FUSED_BLOCKS 782                    // ceil(100000/128); 128 rows per block
#define FACE_BLOCKS 782                     // ceil(200000/256)
#define EDGE_BLOCKS 2344                    // ceil(600000/256)
#define PACK_BLOCKS 64

__device__ __forceinline__ unsigned short f2bf(float f) {
    unsigned int u = __builtin_bit_cast(unsigned int, f);
    u += 0x7fffu + ((u >> 16) & 1u);   // round-to-nearest-even
    return (unsigned short)(u >> 16);
}

// --- K1: per-face normals -> atomicAdd into vertex normal sums + Wlin pack ---
// (replaces linked-list build + k_vnorm walk; normals normalized lazily in k_edge)
__global__ void k_fn(const float* __restrict__ vtx, const int* __restrict__ faces,
                     const float* __restrict__ Wlin,
                     float* __restrict__ nrm,
                     unsigned short* __restrict__ Wb) {
    int b = blockIdx.x;
    int t = threadIdx.x;
    if (b < FACE_BLOCKS) {
        int f = b * 256 + t;
        if (f >= N_F) return;
        int i0 = faces[f], i1 = faces[N_F + f], i2 = faces[2 * N_F + f];
        float ax = vtx[3 * i0], ay = vtx[3 * i0 + 1], az = vtx[3 * i0 + 2];
        float bx = vtx[3 * i1] - ax, by = vtx[3 * i1 + 1] - ay, bz = vtx[3 * i1 + 2] - az;
        float cx = vtx[3 * i2] - ax, cy = vtx[3 * i2 + 1] - ay, cz = vtx[3 * i2 + 2] - az;
        float fx = by * cz - bz * cy;
        float fy = bz * cx - bx * cz;
        float fz = bx * cy - by * cx;
        atomicAdd(&nrm[3 * i0],     fx);
        atomicAdd(&nrm[3 * i0 + 1], fy);
        atomicAdd(&nrm[3 * i0 + 2], fz);
        atomicAdd(&nrm[3 * i1],     fx);
        atomicAdd(&nrm[3 * i1 + 1], fy);
        atomicAdd(&nrm[3 * i1 + 2], fz);
        atomicAdd(&nrm[3 * i2],     fx);
        atomicAdd(&nrm[3 * i2 + 1], fy);
        atomicAdd(&nrm[3 * i2 + 2], fz);
    } else {
        // pack Wlin (fp32 [128,128]) into bf16 MFMA B-fragment order
        int i = (b - FACE_BLOCKS) * 256 + t;   // 0..16383
        int j = i & 7;
        int lane = (i >> 3) & 63;
        int ct = (i >> 9) & 7;
        int kk = i >> 12;
        int k = kk * 32 + (lane >> 4) * 8 + j;
        int n = ct * 16 + (lane & 15);
        Wb[i] = f2bf(Wlin[k * 128 + n]);
    }
}

// --- K3: per-edge MLP -> packed node {src, next+1, w_bf16} in one uint2 ---
// normals arrive as raw area-weighted sums; normalize on read
__global__ void k_edge(const float* __restrict__ vtx, const int* __restrict__ edges,
                       const float* __restrict__ nrm,
                       const float* __restrict__ W1, const float* __restrict__ b1,
                       const float* __restrict__ W2, const float* __restrict__ b2,
                       int* __restrict__ head_e, uint2* __restrict__ enode) {
    __shared__ float sW1[96], sb1[32], sW2[192], sb2[6];
    int t = threadIdx.x;
    if (t < 96)  sW1[t] = W1[t];
    if (t < 32)  sb1[t] = b1[t];
    if (t < 192) sW2[t] = W2[t];
    if (t < 6)   sb2[t] = b2[t];
    __syncthreads();
    int e = blockIdx.x * blockDim.x + t;
    if (e >= N_E) return;
    int s = edges[e], d = edges[N_E + e];
    int old = atomicExch(&head_e[d], e);      // issue early; latency hides under MLP
    float dx = vtx[3 * d] - vtx[3 * s];
    float dy = vtx[3 * d + 1] - vtx[3 * s + 1];
    float dz = vtx[3 * d + 2] - vtx[3 * s + 2];
    float rx = nrm[3 * s], ry = nrm[3 * s + 1], rz = nrm[3 * s + 2];
    float ninv = 1.f / (sqrtf(rx * rx + ry * ry + rz * rz) + 1e-8f);
    float nx = rx * ninv, ny = ry * ninv, nz = rz * ninv;
    float dp = dx * nx + dy * ny + dz * nz;
    float tx = dx - dp * nx, ty = dy - dp * ny, tz = dz - dp * nz;
    float th0 = sb2[0], th1 = sb2[1], th2 = sb2[2], th3 = sb2[3], th4 = sb2[4], th5 = sb2[5];
    #pragma unroll
    for (int j = 0; j < 32; j++) {
        float h = tx * sW1[j] + ty * sW1[32 + j] + tz * sW1[64 + j] + sb1[j];
        h = fmaxf(h, 0.f);
        const float* w2r = &sW2[j * 6];
        th0 += h * w2r[0]; th1 += h * w2r[1]; th2 += h * w2r[2];
        th3 += h * w2r[3]; th4 += h * w2r[4]; th5 += h * w2r[5];
    }
    // S symmetric; q = ||S t||^2
    float ux = th0 * tx + th1 * ty + th2 * tz;
    float uy = th1 * tx + th3 * ty + th4 * tz;
    float uz = th2 * tx + th4 * ty + th5 * tz;
    float q = ux * ux + uy * uy + uz * uz;
    float w = expf(-q);
    unsigned int w16 = f2bf(w);
    uint2 nd;
    nd.x = (unsigned int)(old + 1) | ((w16 & 0xFFFu) << 20);   // next+1 (20b) | w lo12
    nd.y = (unsigned int)s | ((w16 >> 12) << 17);              // src (17b) | w hi4
    enode[e] = nd;
}

// --- K4: FUSED aggregate + GEMM + bias + stats partials.
// Phase 1: each 16-lane group walks FOUR chains interleaved; each lane owns
// 8 floats of the row (2x float4) -> ~12 outstanding loads/lane of MLP.
__global__ __launch_bounds__(512) void k_fused(const float* __restrict__ feat,
                                               const int* __restrict__ head_e,
                                               const uint2* __restrict__ enode,
                                               const unsigned short* __restrict__ Wb,
                                               const float* __restrict__ blin,
                                               float* __restrict__ out,
                                               float* __restrict__ partials) {
    __shared__ __align__(16) unsigned short At[128 * 136];
    __shared__ float gs[128];
    int t = threadIdx.x;
    int g = t >> 4;             // 16-lane group 0..31
    int gl = t & 15;            // lane in group
    int vb = blockIdx.x * 128 + g * 4;   // this group owns rows g*4 .. g*4+3

    float4 a0l = {0,0,0,0}, a0h = {0,0,0,0};
    float4 a1l = {0,0,0,0}, a1h = {0,0,0,0};
    float4 a2l = {0,0,0,0}, a2h = {0,0,0,0};
    float4 a3l = {0,0,0,0}, a3h = {0,0,0,0};
    float d0 = 0.f, d1 = 0.f, d2 = 0.f, d3 = 0.f;
    int e0 = (vb + 0 < N_V) ? head_e[vb + 0] : -1;
    int e1 = (vb + 1 < N_V) ? head_e[vb + 1] : -1;
    int e2 = (vb + 2 < N_V) ? head_e[vb + 2] : -1;
    int e3 = (vb + 3 < N_V) ? head_e[vb + 3] : -1;

    while ((e0 >= 0) || (e1 >= 0) || (e2 >= 0) || (e3 >= 0)) {
        if (e0 >= 0) {
            uint2 nd = enode[e0];
            unsigned int wb = (nd.x >> 20) | (((nd.y >> 17) & 0xFu) << 12);
            float w = __builtin_bit_cast(float, wb << 16);
            const float4* fp = (const float4*)(feat + (size_t)(nd.y & 0x1FFFFu) * 128 + 8 * gl);
            float4 f0 = fp[0], f1 = fp[1];
            a0l.x += w * f0.x; a0l.y += w * f0.y; a0l.z += w * f0.z; a0l.w += w * f0.w;
            a0h.x += w * f1.x; a0h.y += w * f1.y; a0h.z += w * f1.z; a0h.w += w * f1.w;
            d0 += w;
            e0 = (int)(nd.x & 0xFFFFFu) - 1;
        }
        if (e1 >= 0) {
            uint2 nd = enode[e1];
            unsigned int wb = (nd.x >> 20) | (((nd.y >> 17) & 0xFu) << 12);
            float w = __builtin_bit_cast(float, wb << 16);
            const float4* fp = (const float4*)(feat + (size_t)(nd.y & 0x1FFFFu) * 128 + 8 * gl);
            float4 f0 = fp[0], f1 = fp[1];
            a1l.x += w * f0.x; a1l.y += w * f0.y; a1l.z += w * f0.z; a1l.w += w * f0.w;
            a1h.x += w * f1.x; a1h.y += w * f1.y; a1h.z += w * f1.z; a1h.w += w * f1.w;
            d1 += w;
            e1 = (int)(nd.x & 0xFFFFFu) - 1;
        }
        if (e2 >= 0) {
            uint2 nd = enode[e2];
            unsigned int wb = (nd.x >> 20) | (((nd.y >> 17) & 0xFu) << 12);
            float w = __builtin_bit_cast(float, wb << 16);
            const float4* fp = (const float4*)(feat + (size_t)(nd.y & 0x1FFFFu) * 128 + 8 * gl);
            float4 f0 = fp[0], f1 = fp[1];
            a2l.x += w * f0.x; a2l.y += w * f0.y; a2l.z += w * f0.z; a2l.w += w * f0.w;
            a2h.x += w * f1.x; a2h.y += w * f1.y; a2h.z += w * f1.z; a2h.w += w * f1.w;
            d2 += w;
            e2 = (int)(nd.x & 0xFFFFFu) - 1;
        }
        if (e3 >= 0) {
            uint2 nd = enode[e3];
            unsigned int wb = (nd.x >> 20) | (((nd.y >> 17) & 0xFu) << 12);
            float w = __builtin_bit_cast(float, wb << 16);
            const float4* fp = (const float4*)(feat + (size_t)(nd.y & 0x1FFFFu) * 128 + 8 * gl);
            float4 f0 = fp[0], f1 = fp[1];
            a3l.x += w * f0.x; a3l.y += w * f0.y; a3l.z += w * f0.z; a3l.w += w * f0.w;
            a3h.x += w * f1.x; a3h.y += w * f1.y; a3h.z += w * f1.z; a3h.w += w * f1.w;
            d3 += w;
            e3 = (int)(nd.x & 0xFFFFFu) - 1;
        }
    }
    #pragma unroll
    for (int j = 0; j < 4; j++) {
        float4 al = (j == 0) ? a0l : (j == 1) ? a1l : (j == 2) ? a2l : a3l;
        float4 ah = (j == 0) ? a0h : (j == 1) ? a1h : (j == 2) ? a2h : a3h;
        float dn = (j == 0) ? d0 : (j == 1) ? d1 : (j == 2) ? d2 : d3;
        float inv = 1.f / (dn + 1e-5f);
        ushort4 p0, p1;
        p0.x = f2bf(al.x * inv); p0.y = f2bf(al.y * inv);
        p0.z = f2bf(al.z * inv); p0.w = f2bf(al.w * inv);
        p1.x = f2bf(ah.x * inv); p1.y = f2bf(ah.y * inv);
        p1.z = f2bf(ah.z * inv); p1.w = f2bf(ah.w * inv);
        int row = g * 4 + j;
        *(ushort4*)(&At[row * 136 + 8 * gl]) = p0;
        *(ushort4*)(&At[row * 136 + 8 * gl + 4]) = p1;
        if (gl == 0) gs[row] = dn * inv;
    }
    __syncthreads();

    // Phase 2: MFMA. wave id = column tile ct; 8 row tiles of 16.
    int ct = t >> 6;
    int lane = t & 63;
    int m = lane & 15, quad = lane >> 4;
    bf16x8 bfr[4];
    #pragma unroll
    for (int kk = 0; kk < 4; kk++)
        bfr[kk] = *(const bf16x8*)(Wb + (((kk * 8 + ct) * 64 + lane) << 3));
    float bl = blin[ct * 16 + m];
    float ssr = 0.f, qqr = 0.f;
    #pragma unroll
    for (int tile = 0; tile < 8; tile++) {
        f32x4 acc = (f32x4){0.f, 0.f, 0.f, 0.f};
        #pragma unroll
        for (int kk = 0; kk < 4; kk++) {
            bf16x8 af = *(const bf16x8*)(&At[(tile * 16 + m) * 136 + kk * 32 + quad * 8]);
            acc = __builtin_amdgcn_mfma_f32_16x16x32_bf16(af, bfr[kk], acc, 0, 0, 0);
        }
        int r0 = blockIdx.x * 128 + tile * 16;
        #pragma unroll
        for (int reg = 0; reg < 4; reg++) {
            int r = r0 + quad * 4 + reg;
            float g2 = gs[tile * 16 + quad * 4 + reg];
            float val = acc[reg] + bl * g2;
            if (r < N_V) out[(size_t)r * 128 + ct * 16 + m] = val;
            ssr += val; qqr += val * val;   // invalid rows contribute exactly 0
        }
    }
    ssr += __shfl_xor(ssr, 16); qqr += __shfl_xor(qqr, 16);
    ssr += __shfl_xor(ssr, 32); qqr += __shfl_xor(qqr, 32);
    if (quad == 0) {
        partials[(size_t)blockIdx.x * 256 + ct * 16 + m] = ssr;
        partials[(size_t)blockIdx.x * 256 + 128 + ct * 16 + m] = qqr;
    }
}

// --- K5: parallel partials reduction: one wave per column ---
__global__ __launch_bounds__(64) void k_rstats(const float* __restrict__ partials,
                                               float* __restrict__ stats) {
    int c = blockIdx.x;          // 0..127
    int lane = threadIdx.x;      // 0..63
    float s = 0.f, q = 0.f;
    for (int b = lane; b < FUSED_BLOCKS; b += 64) {
        s += partials[(size_t)b * 256 + c];
        q += partials[(size_t)b * 256 + 128 + c];
    }
    #pragma unroll
    for (int off = 32; off; off >>= 1) {
        s += __shfl_down(s, off);
        q += __shfl_down(q, off);
    }
    if (lane == 0) {
        float mu = s * (1.f / N_V);
        float var = (q - s * mu) * (1.f / (N_V - 1));
        float sd = sqrtf(fmaxf(var, 0.f));
        stats[c] = mu;
        stats[128 + c] = 1.f / (sd + 1e-5f);
    }
}

// --- K6: normalize + ELU, in place, float4 ---
__global__ void k_finalize(float* __restrict__ out, const float* __restrict__ stats) {
    int i = blockIdx.x * blockDim.x + threadIdx.x;
    if (i >= N_V * 32) return;
    float4 v = ((float4*)out)[i];
    int c0 = (i * 4) & 127;
    float mu0 = stats[c0], mu1 = stats[c0 + 1], mu2 = stats[c0 + 2], mu3 = stats[c0 + 3];
    float is0 = stats[128 + c0], is1 = stats[128 + c0 + 1], is2 = stats[128 + c0 + 2], is3 = stats[128 + c0 + 3];
    v.x = (v.x - mu0) * is0; v.y = (v.y - mu1) * is1;
    v.z = (v.z - mu2) * is2; v.w = (v.w - mu3) * is3;
    v.x = v.x > 0.f ? v.x : expm1f(v.x);
    v.y = v.y > 0.f ? v.y : expm1f(v.y);
    v.z = v.z > 0.f ? v.z : expm1f(v.z);
    v.w = v.w > 0.f ? v.w : expm1f(v.w);
    ((float4*)out)[i] = v;
}

extern "C" void kernel_launch(void* const* d_in, const int* in_sizes, int n_in,
                              void* d_out, int out_size, void* d_ws, size_t ws_size,
                              hipStream_t stream) {
    const float* feat  = (const float*)d_in[0];
    const float* vtx   = (const float*)d_in[1];
    const int*   edges = (const int*)d_in[2];
    const int*   faces = (const int*)d_in[3];
    const float* W1   = (const float*)d_in[4];
    const float* b1   = (const float*)d_in[5];
    const float* W2   = (const float*)d_in[6];
    const float* b2   = (const float*)d_in[7];
    const float* Wlin = (const float*)d_in[8];
    const float* blin = (const float*)d_in[9];
    float* out = (float*)d_out;

    float* ws = (float*)d_ws;
    // Workspace: peak 2,008,320 floats (8.03 MB) < proven-safe 8.83 MB. Liveness:
    //   head_e   [0..100000)        : memset .. k_fused; stats ALIASES [0..256) after
    //   nrm3     [100000..400000)   : raw normal sums — k_fn .. k_edge
    //   partials [100000..300192)   : ALIAS nrm3 — k_fused .. k_rstats (nrm3 dead)
    //   enode    [500128..1700128)  : k_edge .. k_fused (600000 uint2)
    //   Wb       [2000128..2008320) : k_fn .. k_fused (16384 shorts)
    int*   head_e   = (int*)ws;                              // 100000
    float* nrm3     = ws + 100000;                           // 300000
    float* partials = ws + 100000;                           // 200192 (alias)
    uint2* enode    = (uint2*)(ws + 500128);                 // 600000 uint2
    unsigned short* Wb = (unsigned short*)(ws + 2000128);    // 16384 shorts
    float* stats    = ws;                                    // 256 (alias, head_e dead)

    hipMemsetAsync(head_e, 0xFF, 100000 * sizeof(int), stream);
    hipMemsetAsync(nrm3, 0, 300000 * sizeof(float), stream);

    k_fn<<<FACE_BLOCKS + PACK_BLOCKS, 256, 0, stream>>>(vtx, faces, Wlin, nrm3, Wb);
    k_edge<<<EDGE_BLOCKS, 256, 0, stream>>>(vtx, edges, nrm3, W1, b1, W2, b2,
                                            head_e, enode);
    k_fused<<<FUSED_BLOCKS, 512, 0, stream>>>(feat, head_e, enode, Wb, blin,
                                              out, partials);
    k_rstats<<<128, 64, 0, stream>>>(partials, stats);
    k_finalize<<<(N_V * 32 + 255) / 256, 256, 0, stream>>>(out, stats);
}

// Round 3
// 263.262 us; speedup vs baseline: 1.2061x; 1.2061x over previous
//
#include <hip/hip_runtime.h>
#include <hip/hip_bf16.h>
#include <math.h>

#define N_V 100000
#define N_E 600000
#define N_F 200000
// CIN = COUT = 128, H = 32

typedef __attribute__((ext_vector_type(8))) short bf16x8;
typedef __attribute__((ext_vector_type(4))) float f32x4;

#define FUSED_BLOCKS 782                    // ceil(100000/128); 128 rows per block
#define FACE_BLOCKS 782                     // ceil(200000/256)
#define EDGE_BLOCKS 2344                    // ceil(600000/256)
#define PACK_BLOCKS 64

__device__ __forceinline__ unsigned short f2bf(float f) {
    unsigned int u = __builtin_bit_cast(unsigned int, f);
    u += 0x7fffu + ((u >> 16) & 1u);   // round-to-nearest-even
    return (unsigned short)(u >> 16);
}

// --- K1: per-face normals (float4, streamed) + corner linked-list push + Wlin pack ---
// (atomicAdd variant measured 97us @ 18.6G atomics/s — list build is cheaper; reverted)
__global__ void k_fn(const float* __restrict__ vtx, const int* __restrict__ faces,
                     const float* __restrict__ Wlin,
                     float4* __restrict__ fnbuf4,
                     int* __restrict__ head_f, int* __restrict__ next_f,
                     unsigned short* __restrict__ Wb) {
    int b = blockIdx.x;
    int t = threadIdx.x;
    if (b < FACE_BLOCKS) {
        int f = b * 256 + t;
        if (f >= N_F) return;
        int i0 = faces[f], i1 = faces[N_F + f], i2 = faces[2 * N_F + f];
        // push corners first so the exch latency overlaps the vtx gathers
        #pragma unroll
        for (int j = 0; j < 3; j++) {
            int v = (j == 0) ? i0 : (j == 1 ? i1 : i2);
            int c = 3 * f + j;
            int old = atomicExch(&head_f[v], c);
            next_f[c] = old;
        }
        float ax = vtx[3 * i0], ay = vtx[3 * i0 + 1], az = vtx[3 * i0 + 2];
        float bx = vtx[3 * i1] - ax, by = vtx[3 * i1 + 1] - ay, bz = vtx[3 * i1 + 2] - az;
        float cx = vtx[3 * i2] - ax, cy = vtx[3 * i2 + 1] - ay, cz = vtx[3 * i2 + 2] - az;
        float4 fn;
        fn.x = by * cz - bz * cy;
        fn.y = bz * cx - bx * cz;
        fn.z = bx * cy - by * cx;
        fn.w = 0.f;
        fnbuf4[f] = fn;
    } else {
        // pack Wlin (fp32 [128,128]) into bf16 MFMA B-fragment order
        int i = (b - FACE_BLOCKS) * 256 + t;   // 0..16383
        int j = i & 7;
        int lane = (i >> 3) & 63;
        int ct = (i >> 9) & 7;
        int kk = i >> 12;
        int k = kk * 32 + (lane >> 4) * 8 + j;
        int n = ct * 16 + (lane & 15);
        Wb[i] = f2bf(Wlin[k * 128 + n]);
    }
}

// --- K2: vertex normals via corner-list walk; output float4 (coalesced, vec-gatherable) ---
__global__ void k_vnorm(const float4* __restrict__ fnbuf4,
                        const int* __restrict__ head_f, const int* __restrict__ next_f,
                        float4* __restrict__ nrm4) {
    int v = blockIdx.x * 256 + threadIdx.x;
    if (v >= N_V) return;
    float nx = 0.f, ny = 0.f, nz = 0.f;
    int c = head_f[v];
    while (c >= 0) {
        float4 fn = fnbuf4[(unsigned)c / 3u];
        nx += fn.x; ny += fn.y; nz += fn.z;
        c = next_f[c];
    }
    float inv = 1.f / (sqrtf(nx * nx + ny * ny + nz * nz) + 1e-8f);
    float4 o;
    o.x = nx * inv; o.y = ny * inv; o.z = nz * inv; o.w = 0.f;
    nrm4[v] = o;
}

// --- K3: per-edge MLP -> packed node {src, next+1, w_bf16} in one uint2 ---
__global__ void k_edge(const float* __restrict__ vtx, const int* __restrict__ edges,
                       const float4* __restrict__ nrm4,
                       const float* __restrict__ W1, const float* __restrict__ b1,
                       const float* __restrict__ W2, const float* __restrict__ b2,
                       int* __restrict__ head_e, uint2* __restrict__ enode) {
    __shared__ float sW1[96], sb1[32], sW2[192], sb2[6];
    int t = threadIdx.x;
    if (t < 96)  sW1[t] = W1[t];
    if (t < 32)  sb1[t] = b1[t];
    if (t < 192) sW2[t] = W2[t];
    if (t < 6)   sb2[t] = b2[t];
    __syncthreads();
    int e = blockIdx.x * blockDim.x + t;
    if (e >= N_E) return;
    int s = edges[e], d = edges[N_E + e];
    int old = atomicExch(&head_e[d], e);      // issue early; latency hides under MLP
    float4 nv = nrm4[s];                      // one 16B gather instead of 3 scalars
    float dx = vtx[3 * d] - vtx[3 * s];
    float dy = vtx[3 * d + 1] - vtx[3 * s + 1];
    float dz = vtx[3 * d + 2] - vtx[3 * s + 2];
    float nx = nv.x, ny = nv.y, nz = nv.z;
    float dp = dx * nx + dy * ny + dz * nz;
    float tx = dx - dp * nx, ty = dy - dp * ny, tz = dz - dp * nz;
    float th0 = sb2[0], th1 = sb2[1], th2 = sb2[2], th3 = sb2[3], th4 = sb2[4], th5 = sb2[5];
    #pragma unroll
    for (int j = 0; j < 32; j++) {
        float h = tx * sW1[j] + ty * sW1[32 + j] + tz * sW1[64 + j] + sb1[j];
        h = fmaxf(h, 0.f);
        const float* w2r = &sW2[j * 6];
        th0 += h * w2r[0]; th1 += h * w2r[1]; th2 += h * w2r[2];
        th3 += h * w2r[3]; th4 += h * w2r[4]; th5 += h * w2r[5];
    }
    // S symmetric; q = ||S t||^2
    float ux = th0 * tx + th1 * ty + th2 * tz;
    float uy = th1 * tx + th3 * ty + th4 * tz;
    float uz = th2 * tx + th4 * ty + th5 * tz;
    float q = ux * ux + uy * uy + uz * uz;
    float w = expf(-q);
    unsigned int w16 = f2bf(w);
    uint2 nd;
    nd.x = (unsigned int)(old + 1) | ((w16 & 0xFFFu) << 20);   // next+1 (20b) | w lo12
    nd.y = (unsigned int)s | ((w16 >> 12) << 17);              // src (17b) | w hi4
    enode[e] = nd;
}

// --- K4: FUSED aggregate + GEMM + bias + stats partials.
// Phase 1: each 16-lane group walks FOUR chains interleaved; each lane owns
// 8 floats of the row (2x float4) -> ~12 outstanding loads/lane of MLP.
__global__ __launch_bounds__(512) void k_fused(const float* __restrict__ feat,
                                               const int* __restrict__ head_e,
                                               const uint2* __restrict__ enode,
                                               const unsigned short* __restrict__ Wb,
                                               const float* __restrict__ blin,
                                               float* __restrict__ out,
                                               float* __restrict__ partials) {
    __shared__ __align__(16) unsigned short At[128 * 136];
    __shared__ float gs[128];
    int t = threadIdx.x;
    int g = t >> 4;             // 16-lane group 0..31
    int gl = t & 15;            // lane in group
    int vb = blockIdx.x * 128 + g * 4;   // this group owns rows g*4 .. g*4+3

    float4 a0l = {0,0,0,0}, a0h = {0,0,0,0};
    float4 a1l = {0,0,0,0}, a1h = {0,0,0,0};
    float4 a2l = {0,0,0,0}, a2h = {0,0,0,0};
    float4 a3l = {0,0,0,0}, a3h = {0,0,0,0};
    float d0 = 0.f, d1 = 0.f, d2 = 0.f, d3 = 0.f;
    int e0 = (vb + 0 < N_V) ? head_e[vb + 0] : -1;
    int e1 = (vb + 1 < N_V) ? head_e[vb + 1] : -1;
    int e2 = (vb + 2 < N_V) ? head_e[vb + 2] : -1;
    int e3 = (vb + 3 < N_V) ? head_e[vb + 3] : -1;

    while ((e0 >= 0) || (e1 >= 0) || (e2 >= 0) || (e3 >= 0)) {
        if (e0 >= 0) {
            uint2 nd = enode[e0];
            unsigned int wb = (nd.x >> 20) | (((nd.y >> 17) & 0xFu) << 12);
            float w = __builtin_bit_cast(float, wb << 16);
            const float4* fp = (const float4*)(feat + (size_t)(nd.y & 0x1FFFFu) * 128 + 8 * gl);
            float4 f0 = fp[0], f1 = fp[1];
            a0l.x += w * f0.x; a0l.y += w * f0.y; a0l.z += w * f0.z; a0l.w += w * f0.w;
            a0h.x += w * f1.x; a0h.y += w * f1.y; a0h.z += w * f1.z; a0h.w += w * f1.w;
            d0 += w;
            e0 = (int)(nd.x & 0xFFFFFu) - 1;
        }
        if (e1 >= 0) {
            uint2 nd = enode[e1];
            unsigned int wb = (nd.x >> 20) | (((nd.y >> 17) & 0xFu) << 12);
            float w = __builtin_bit_cast(float, wb << 16);
            const float4* fp = (const float4*)(feat + (size_t)(nd.y & 0x1FFFFu) * 128 + 8 * gl);
            float4 f0 = fp[0], f1 = fp[1];
            a1l.x += w * f0.x; a1l.y += w * f0.y; a1l.z += w * f0.z; a1l.w += w * f0.w;
            a1h.x += w * f1.x; a1h.y += w * f1.y; a1h.z += w * f1.z; a1h.w += w * f1.w;
            d1 += w;
            e1 = (int)(nd.x & 0xFFFFFu) - 1;
        }
        if (e2 >= 0) {
            uint2 nd = enode[e2];
            unsigned int wb = (nd.x >> 20) | (((nd.y >> 17) & 0xFu) << 12);
            float w = __builtin_bit_cast(float, wb << 16);
            const float4* fp = (const float4*)(feat + (size_t)(nd.y & 0x1FFFFu) * 128 + 8 * gl);
            float4 f0 = fp[0], f1 = fp[1];
            a2l.x += w * f0.x; a2l.y += w * f0.y; a2l.z += w * f0.z; a2l.w += w * f0.w;
            a2h.x += w * f1.x; a2h.y += w * f1.y; a2h.z += w * f1.z; a2h.w += w * f1.w;
            d2 += w;
            e2 = (int)(nd.x & 0xFFFFFu) - 1;
        }
        if (e3 >= 0) {
            uint2 nd = enode[e3];
            unsigned int wb = (nd.x >> 20) | (((nd.y >> 17) & 0xFu) << 12);
            float w = __builtin_bit_cast(float, wb << 16);
            const float4* fp = (const float4*)(feat + (size_t)(nd.y & 0x1FFFFu) * 128 + 8 * gl);
            float4 f0 = fp[0], f1 = fp[1];
            a3l.x += w * f0.x; a3l.y += w * f0.y; a3l.z += w * f0.z; a3l.w += w * f0.w;
            a3h.x += w * f1.x; a3h.y += w * f1.y; a3h.z += w * f1.z; a3h.w += w * f1.w;
            d3 += w;
            e3 = (int)(nd.x & 0xFFFFFu) - 1;
        }
    }
    #pragma unroll
    for (int j = 0; j < 4; j++) {
        float4 al = (j == 0) ? a0l : (j == 1) ? a1l : (j == 2) ? a2l : a3l;
        float4 ah = (j == 0) ? a0h : (j == 1) ? a1h : (j == 2) ? a2h : a3h;
        float dn = (j == 0) ? d0 : (j == 1) ? d1 : (j == 2) ? d2 : d3;
        float inv = 1.f / (dn + 1e-5f);
        ushort4 p0, p1;
        p0.x = f2bf(al.x * inv); p0.y = f2bf(al.y * inv);
        p0.z = f2bf(al.z * inv); p0.w = f2bf(al.w * inv);
        p1.x = f2bf(ah.x * inv); p1.y = f2bf(ah.y * inv);
        p1.z = f2bf(ah.z * inv); p1.w = f2bf(ah.w * inv);
        int row = g * 4 + j;
        *(ushort4*)(&At[row * 136 + 8 * gl]) = p0;
        *(ushort4*)(&At[row * 136 + 8 * gl + 4]) = p1;
        if (gl == 0) gs[row] = dn * inv;
    }
    __syncthreads();

    // Phase 2: MFMA. wave id = column tile ct; 8 row tiles of 16.
    int ct = t >> 6;
    int lane = t & 63;
    int m = lane & 15, quad = lane >> 4;
    bf16x8 bfr[4];
    #pragma unroll
    for (int kk = 0; kk < 4; kk++)
        bfr[kk] = *(const bf16x8*)(Wb + (((kk * 8 + ct) * 64 + lane) << 3));
    float bl = blin[ct * 16 + m];
    float ssr = 0.f, qqr = 0.f;
    #pragma unroll
    for (int tile = 0; tile < 8; tile++) {
        f32x4 acc = (f32x4){0.f, 0.f, 0.f, 0.f};
        #pragma unroll
        for (int kk = 0; kk < 4; kk++) {
            bf16x8 af = *(const bf16x8*)(&At[(tile * 16 + m) * 136 + kk * 32 + quad * 8]);
            acc = __builtin_amdgcn_mfma_f32_16x16x32_bf16(af, bfr[kk], acc, 0, 0, 0);
        }
        int r0 = blockIdx.x * 128 + tile * 16;
        #pragma unroll
        for (int reg = 0; reg < 4; reg++) {
            int r = r0 + quad * 4 + reg;
            float g2 = gs[tile * 16 + quad * 4 + reg];
            float val = acc[reg] + bl * g2;
            if (r < N_V) out[(size_t)r * 128 + ct * 16 + m] = val;
            ssr += val; qqr += val * val;   // invalid rows contribute exactly 0
        }
    }
    ssr += __shfl_xor(ssr, 16); qqr += __shfl_xor(qqr, 16);
    ssr += __shfl_xor(ssr, 32); qqr += __shfl_xor(qqr, 32);
    if (quad == 0) {
        partials[(size_t)blockIdx.x * 256 + ct * 16 + m] = ssr;
        partials[(size_t)blockIdx.x * 256 + 128 + ct * 16 + m] = qqr;
    }
}

// --- K5: parallel partials reduction: one wave per column ---
__global__ __launch_bounds__(64) void k_rstats(const float* __restrict__ partials,
                                               float* __restrict__ stats) {
    int c = blockIdx.x;          // 0..127
    int lane = threadIdx.x;      // 0..63
    float s = 0.f, q = 0.f;
    for (int b = lane; b < FUSED_BLOCKS; b += 64) {
        s += partials[(size_t)b * 256 + c];
        q += partials[(size_t)b * 256 + 128 + c];
    }
    #pragma unroll
    for (int off = 32; off; off >>= 1) {
        s += __shfl_down(s, off);
        q += __shfl_down(q, off);
    }
    if (lane == 0) {
        float mu = s * (1.f / N_V);
        float var = (q - s * mu) * (1.f / (N_V - 1));
        float sd = sqrtf(fmaxf(var, 0.f));
        stats[c] = mu;
        stats[128 + c] = 1.f / (sd + 1e-5f);
    }
}

// --- K6: normalize + ELU, in place, float4 ---
__global__ void k_finalize(float* __restrict__ out, const float* __restrict__ stats) {
    int i = blockIdx.x * blockDim.x + threadIdx.x;
    if (i >= N_V * 32) return;
    float4 v = ((float4*)out)[i];
    int c0 = (i * 4) & 127;
    float mu0 = stats[c0], mu1 = stats[c0 + 1], mu2 = stats[c0 + 2], mu3 = stats[c0 + 3];
    float is0 = stats[128 + c0], is1 = stats[128 + c0 + 1], is2 = stats[128 + c0 + 2], is3 = stats[128 + c0 + 3];
    v.x = (v.x - mu0) * is0; v.y = (v.y - mu1) * is1;
    v.z = (v.z - mu2) * is2; v.w = (v.w - mu3) * is3;
    v.x = v.x > 0.f ? v.x : expm1f(v.x);
    v.y = v.y > 0.f ? v.y : expm1f(v.y);
    v.z = v.z > 0.f ? v.z : expm1f(v.z);
    v.w = v.w > 0.f ? v.w : expm1f(v.w);
    ((float4*)out)[i] = v;
}

extern "C" void kernel_launch(void* const* d_in, const int* in_sizes, int n_in,
                              void* d_out, int out_size, void* d_ws, size_t ws_size,
                              hipStream_t stream) {
    const float* feat  = (const float*)d_in[0];
    const float* vtx   = (const float*)d_in[1];
    const int*   edges = (const int*)d_in[2];
    const int*   faces = (const int*)d_in[3];
    const float* W1   = (const float*)d_in[4];
    const float* b1   = (const float*)d_in[5];
    const float* W2   = (const float*)d_in[6];
    const float* b2   = (const float*)d_in[7];
    const float* Wlin = (const float*)d_in[8];
    const float* blin = (const float*)d_in[9];
    float* out = (float*)d_out;

    float* ws = (float*)d_ws;
    // Workspace: peak 2,108,320 floats (8.43 MB) < proven-safe 8.83 MB. Liveness:
    //   head_e   [0..100000)        : memset .. k_fused; stats ALIASES [0..256) after
    //   nrm4     [100000..500000)   : k_vnorm .. k_edge (float4 x 100000)
    //   partials [100000..300192)   : ALIAS nrm4 — k_fused .. k_rstats (nrm4 dead)
    //   big region [500128..2000128): stage A/B = head_f(100k)+next_f(600k)+fnbuf4(800k)
    //                                 stage C/D = enode(1.2M) aliases its head
    //   Wb       [2000128..2008320) : k_fn .. k_fused (16384 shorts)
    int*   head_e   = (int*)ws;                              // 100000
    float4* nrm4    = (float4*)(ws + 100000);                // 100000 float4
    float* partials = ws + 100000;                           // 200192 (alias)
    int*   head_f   = (int*)(ws + 500128);                   // 100000
    int*   next_f   = (int*)(ws + 600128);                   // 600000
    float4* fnbuf4  = (float4*)(ws + 1200128);               // 200000 float4
    uint2* enode    = (uint2*)(ws + 500128);                 // 600000 uint2 (alias)
    unsigned short* Wb = (unsigned short*)(ws + 2000128);    // 16384 shorts
    float* stats    = ws;                                    // 256 (alias, head_e dead)

    hipMemsetAsync(head_e, 0xFF, 100000 * sizeof(int), stream);
    hipMemsetAsync(head_f, 0xFF, 100000 * sizeof(int), stream);

    k_fn<<<FACE_BLOCKS + PACK_BLOCKS, 256, 0, stream>>>(vtx, faces, Wlin, fnbuf4,
                                                        head_f, next_f, Wb);
    k_vnorm<<<(N_V + 255) / 256, 256, 0, stream>>>(fnbuf4, head_f, next_f, nrm4);
    k_edge<<<EDGE_BLOCKS, 256, 0, stream>>>(vtx, edges, nrm4, W1, b1, W2, b2,
                                            head_e, enode);
    k_fused<<<FUSED_BLOCKS, 512, 0, stream>>>(feat, head_e, enode, Wb, blin,
                                              out, partials);
    k_rstats<<<128, 64, 0, stream>>>(partials, stats);
    k_finalize<<<(N_V * 32 + 255) / 256, 256, 0, stream>>>(out, stats);
}